// Round 9
// baseline (1658.733 us; speedup 1.0000x reference)
//
#include <hip/hip_runtime.h>

// FeedBack LSTM: B=1024, T_in=128, F=3, UNITS=256, out_steps=32.
// R9 = R6 chassis (2-member column partition, AGPR-resident weights, quiet
// counter protocol) with the exchange critical path shortened:
//  - per-WAVE polling (8 lane-0 pollers, 4B each): no detect barrier
//  - producer: per-wave vmcnt(0) drain + lane-0 atomicAdd (8/step), no
//    publish barrier + no tid0 serialization
//  - peer data load (1 u64/thread, issued once after confirmation) overlapped
//    with the 16 own-half MFMAs (+x@Wk in warmup)
//  - barriers/step: 4-5 -> 2 (warmup) / 3 (decode)
// Protocol safety identical to R6: per-wave counter bump only after that
// wave's data stores drained (vmcnt 0); flag-visible => data-visible; parity
// + counter ordering prevents overwrite-before-read.

#define TIN    128
#define FIN    3
#define OSTEPS 32
#define LASTT  (TIN + OSTEPS - 1)   // t = 0..159; t==159 is head-only

typedef float    f32x4 __attribute__((ext_vector_type(4)));
typedef _Float16 half8 __attribute__((ext_vector_type(8)));
typedef unsigned long long u64;
typedef unsigned int u32;

__device__ __forceinline__ float fast_rcp(float x) { return __builtin_amdgcn_rcpf(x); }
__device__ __forceinline__ float sigm(float x)  { return fast_rcp(1.0f + __expf(-x)); }
__device__ __forceinline__ float tanh_f(float x){ return 1.0f - 2.0f * fast_rcp(__expf(2.0f * x) + 1.0f); }

// Pack Wr [256][1024] fp32 -> fp16 B-frags. Tile T = p*32 + q*8 + w covers
// cols q*256 + p*128 + w*16 + (l&15); k = kt*32 + (l>>4)*8 + j.
// P[(T*8+kt)*512 + l*8 + j] = Wr[k][col]
__global__ __launch_bounds__(512) void pack_wr(const float* __restrict__ Wr,
                                               _Float16* __restrict__ P)
{
    int idx = blockIdx.x * 512 + threadIdx.x;   // 64 blocks -> 32768
    int l   = idx & 63;
    int kt  = (idx >> 6) & 7;
    int T   = idx >> 9;                         // 0..63
    int p = T >> 5, q = (T >> 3) & 3, w = T & 7;
    int col = q * 256 + p * 128 + w * 16 + (l & 15);
    int k0  = kt * 32 + (l >> 4) * 8;
    half8 v;
#pragma unroll
    for (int j = 0; j < 8; ++j) v[j] = (_Float16)Wr[(k0 + j) * 1024 + col];
    *reinterpret_cast<half8*>(P + (size_t)idx * 8) = v;
}

__global__ __launch_bounds__(512, 2) void lstm_pair(
    const float* __restrict__ x_in,   // [1024][128][3]
    const float* __restrict__ Wk,     // [3][1024]
    const float* __restrict__ bias,   // [1024]
    const float* __restrict__ Wd,     // [256][3]
    const float* __restrict__ bd,     // [3]
    const _Float16* __restrict__ WrP, // packed B-frags
    u64*       __restrict__ hex,      // [2 par][64 grp][2 mem][512] u64 h-halves
    unsigned*  __restrict__ flags,    // [64 grp][2 mem] counters, 64B apart
    float* __restrict__ out)          // [1024][32][3]
{
    __shared__ float                xs[16 * TIN * FIN];  // 24 KB staged inputs
    __shared__ alignas(16) _Float16 hfull[2][4096];      // full h, A-frag order
    __shared__ float                pred_buf[16][4];     // fed-back prediction

    const int tid  = threadIdx.x;
    const int w    = tid >> 6;            // wave 0..7
    const int l    = tid & 63;
    const int n    = l & 15;
    const int row0 = (l >> 4) * 4;        // MFMA C rows for this lane
    const int bid  = blockIdx.x;
    const int p    = (bid >> 3) & 1;      // member: units [p*128,(p+1)*128)
    const int pp   = 1 - p;
    const int g    = (bid & 7) + 8 * (bid >> 4);   // group 0..63; pair = same XCD

    // ---- prologue ----
    const float* xsrc = x_in + (size_t)g * 16 * TIN * FIN;
    for (int i = tid; i < 16 * TIN * FIN; i += 512) xs[i] = xsrc[i];

    half8 bfr[4][8];                      // weight slice (lives in AGPRs)
#pragma unroll
    for (int q = 0; q < 4; ++q)
#pragma unroll
        for (int kt = 0; kt < 8; ++kt)
            bfr[q][kt] = *reinterpret_cast<const half8*>(
                WrP + (((size_t)(p * 32 + q * 8 + w) * 8 + kt) * 512 + l * 8));

    float b_r[4], wk_r[4][3];
#pragma unroll
    for (int q = 0; q < 4; ++q) {
        int col = q * 256 + p * 128 + w * 16 + n;
        b_r[q] = bias[col];
#pragma unroll
        for (int f = 0; f < 3; ++f) wk_r[q][f] = Wk[f * 1024 + col];
    }
    float wd_r[4][3];                     // head: lane l covers units 4l..4l+3
#pragma unroll
    for (int j = 0; j < 4; ++j)
#pragma unroll
        for (int f = 0; f < 3; ++f) wd_r[j][f] = Wd[(4 * l + j) * 3 + f];
    const float bd0 = bd[0], bd1 = bd[1], bd2 = bd[2];

    float c_st[4] = {0.f, 0.f, 0.f, 0.f};
    const int hloc = (w >> 1) * 512 + ((2 * w + (n >> 3)) & 3) * 128
                   + row0 * 8 + (n & 7);
    const int hpos = p * 2048 + hloc;     // own h position in hfull

    unsigned* cnt_my   = flags + ((size_t)g * 2 + p)  * 16;
    unsigned* cnt_peer = flags + ((size_t)g * 2 + pp) * 16;

    __syncthreads();

    for (int t = 0; t <= LASTT; ++t) {
        const int par_rd = (t - 1) & 1;   // parity holding h_{t-1} (t>0)
        const bool dec = (t >= TIN);

        f32x4 acc[4];
#pragma unroll
        for (int q = 0; q < 4; ++q)
#pragma unroll
            for (int r = 0; r < 4; ++r) acc[q][r] = b_r[q];

        if (t > 0) {
            // ---- per-wave detect (quiet: 1 lane, 4B per retry) ----
            if (l == 0) {
                while (__hip_atomic_load(cnt_peer, __ATOMIC_RELAXED,
                                         __HIP_MEMORY_SCOPE_AGENT) < (u32)(8 * t)) { }
            }
            asm volatile("" ::: "memory");      // pin data load after the spin
            // ---- issue peer data load (once), overlap with own-half work ----
            u64 pv = __hip_atomic_load(
                hex + (((size_t)par_rd * 64 + g) * 2 + pp) * 512 + tid,
                __ATOMIC_RELAXED, __HIP_MEMORY_SCOPE_AGENT);

            if (!dec) {                         // warmup: x@Wk under the load
#pragma unroll
                for (int r = 0; r < 4; ++r) {
                    const float* xp = &xs[((row0 + r) * TIN + t) * 3];
                    float x0 = xp[0], x1 = xp[1], x2 = xp[2];
#pragma unroll
                    for (int q = 0; q < 4; ++q)
                        acc[q][r] += x0 * wk_r[q][0] + x1 * wk_r[q][1] + x2 * wk_r[q][2];
                }
            }
            // own-half MFMAs (hfull[par_rd] own region: valid since prev B3)
#pragma unroll
            for (int kk = 0; kk < 4; ++kk) {
                half8 a = *reinterpret_cast<const half8*>(
                    &hfull[par_rd][(4 * p + kk) * 512 + l * 8]);
#pragma unroll
                for (int q = 0; q < 4; ++q)
                    acc[q] = __builtin_amdgcn_mfma_f32_16x16x32_f16(a, bfr[q][4 * p + kk], acc[q], 0, 0, 0);
            }
            // land peer half into LDS
            reinterpret_cast<u64*>(&hfull[par_rd][pp * 2048])[tid] = pv;
            __syncthreads();                    // B1: peer half broadcast
        } else {
            // t == 0: h = 0, only b + x@Wk
#pragma unroll
            for (int r = 0; r < 4; ++r) {
                const float* xp = &xs[((row0 + r) * TIN + 0) * 3];
                float x0 = xp[0], x1 = xp[1], x2 = xp[2];
#pragma unroll
                for (int q = 0; q < 4; ++q)
                    acc[q][r] += x0 * wk_r[q][0] + x1 * wk_r[q][1] + x2 * wk_r[q][2];
            }
        }

        // ---- head phase (t>=128): pred_s from h_{t-1}, s = t-128 ----
        if (dec) {
            const int s = t - TIN;
#pragma unroll
            for (int rr = 0; rr < 2; ++rr) {
                int row = 2 * w + rr;           // wave w reduces batch rows 2w, 2w+1
                const _Float16* hb = &hfull[par_rd][(l >> 3) * 512
                                   + ((l >> 1) & 3) * 128 + row * 8 + 4 * (l & 1)];
                float p0 = 0.f, p1 = 0.f, p2 = 0.f;
#pragma unroll
                for (int j = 0; j < 4; ++j) {
                    float hj = (float)hb[j];
                    p0 += hj * wd_r[j][0];
                    p1 += hj * wd_r[j][1];
                    p2 += hj * wd_r[j][2];
                }
#pragma unroll
                for (int o = 32; o > 0; o >>= 1) {
                    p0 += __shfl_xor(p0, o);
                    p1 += __shfl_xor(p1, o);
                    p2 += __shfl_xor(p2, o);
                }
                if (l == 0) {
                    p0 += bd0; p1 += bd1; p2 += bd2;
                    pred_buf[row][0] = p0; pred_buf[row][1] = p1; pred_buf[row][2] = p2;
                    if (p == 0) {
                        float* op = out + ((size_t)(g * 16 + row) * OSTEPS + s) * 3;
                        op[0] = p0; op[1] = p1; op[2] = p2;
                    }
                }
            }
            __syncthreads();                    // B2: pred_buf ready
            if (t == LASTT) break;              // s=31 stored; done
            // decode x@Wk with x = pred
#pragma unroll
            for (int r = 0; r < 4; ++r) {
                float x0 = pred_buf[row0 + r][0];
                float x1 = pred_buf[row0 + r][1];
                float x2 = pred_buf[row0 + r][2];
#pragma unroll
                for (int q = 0; q < 4; ++q)
                    acc[q][r] += x0 * wk_r[q][0] + x1 * wk_r[q][1] + x2 * wk_r[q][2];
            }
        }

        // ---- peer-half MFMAs ----
        if (t > 0) {
#pragma unroll
            for (int kk = 0; kk < 4; ++kk) {
                half8 a = *reinterpret_cast<const half8*>(
                    &hfull[par_rd][(4 * pp + kk) * 512 + l * 8]);
#pragma unroll
                for (int q = 0; q < 4; ++q)
                    acc[q] = __builtin_amdgcn_mfma_f32_16x16x32_f16(a, bfr[q][4 * pp + kk], acc[q], 0, 0, 0);
            }
        }

        // ---- gates (in-lane), c update, own-half h -> LDS ----
        const int par_wr = t & 1;
#pragma unroll
        for (int r = 0; r < 4; ++r) {
            float iv = sigm(acc[0][r]);
            float fv = sigm(acc[1][r]);
            float gv = tanh_f(acc[2][r]);
            float ov = sigm(acc[3][r]);
            float cc = fv * c_st[r] + iv * gv;
            c_st[r] = cc;
            hfull[par_wr][hpos + r * 8] = (_Float16)(ov * tanh_f(cc));
        }
        __syncthreads();                        // B3: own half complete in LDS

        // ---- publish: coalesced u64 stores; per-wave drain + counter bump ----
        {
            u64 d = reinterpret_cast<const u64*>(&hfull[par_wr][p * 2048])[tid];
            __hip_atomic_store(
                hex + (((size_t)par_wr * 64 + g) * 2 + p) * 512 + tid, d,
                __ATOMIC_RELAXED, __HIP_MEMORY_SCOPE_AGENT);
        }
        asm volatile("s_waitcnt vmcnt(0)" ::: "memory");   // wave-local drain
        if (l == 0)
            __hip_atomic_fetch_add(cnt_my, 1u, __ATOMIC_RELAXED,
                                   __HIP_MEMORY_SCOPE_AGENT);
    }
}

extern "C" void kernel_launch(void* const* d_in, const int* in_sizes, int n_in,
                              void* d_out, int out_size, void* d_ws, size_t ws_size,
                              hipStream_t stream)
{
    const float* x  = (const float*)d_in[0];
    const float* Wk = (const float*)d_in[1];
    const float* Wr = (const float*)d_in[2];
    const float* b  = (const float*)d_in[3];
    const float* Wd = (const float*)d_in[4];
    const float* bd = (const float*)d_in[5];
    float* out = (float*)d_out;

    // d_ws: [0,8K) flags | [8K, 8K+512K) WrP | [8K+512K, +1M) hex
    unsigned* flags = (unsigned*)d_ws;
    _Float16* WrP   = (_Float16*)((char*)d_ws + 8192);
    u64*      hex   = (u64*)((char*)d_ws + 8192 + 524288);

    hipMemsetAsync(d_ws, 0, 8192, stream);          // zero group counters
    pack_wr<<<64, 512, 0, stream>>>(Wr, WrP);
    lstm_pair<<<128, 512, 0, stream>>>(x, Wk, b, Wd, bd, WrP, hex, flags, out);
}

// Round 10
// 1476.854 us; speedup vs baseline: 1.1232x; 1.1232x over previous
//
#include <hip/hip_runtime.h>

// FeedBack LSTM: B=1024, T_in=128, F=3, UNITS=256, out_steps=32.
// R10: 2-member column partition + AGPR-resident weights (R6 chassis) with a
// ONE-SHOT LATE TAGGED exchange:
//   publish: after B3, thread tid reads its contiguous 8B of own-half h from
//            LDS and stores 2 tagged u64s (h16<<16|t per word) -- coalesced.
//   acquire: own-half MFMAs (+x@Wk in warmup) run FIRST; then (sched_barrier
//            pinned) one bulk tagged load; per-thread predicated retry with
//            s_sleep(4) backoff only for threads whose tags missed.
//   Lessons encoded: R8 (early spec load => lockstep retry storm), R9 (multi-
//   lane hot polling floods fabric), R6 (3.5 serial RTs too many).
// Safety: parity slots + strictly-increasing tags (R7's argument): member
// overwrites parity slot with tag t+2 only after consuming peer's t+1, which
// peer published only after consuming our t. Tags: t<=159 < 0xFFFF init.

#define TIN    128
#define FIN    3
#define OSTEPS 32
#define LASTT  (TIN + OSTEPS - 1)   // t = 0..159; t==159 is head-only

typedef float    f32x4 __attribute__((ext_vector_type(4)));
typedef _Float16 half8 __attribute__((ext_vector_type(8)));
typedef unsigned long long u64;
typedef unsigned int u32;

__device__ __forceinline__ float fast_rcp(float x) { return __builtin_amdgcn_rcpf(x); }
__device__ __forceinline__ float sigm(float x)  { return fast_rcp(1.0f + __expf(-x)); }
__device__ __forceinline__ float tanh_f(float x){ return 1.0f - 2.0f * fast_rcp(__expf(2.0f * x) + 1.0f); }

// Pack Wr [256][1024] fp32 -> fp16 B-frags. Tile T = p*32 + q*8 + w covers
// cols q*256 + p*128 + w*16 + (l&15); k = kt*32 + (l>>4)*8 + j.
// P[(T*8+kt)*512 + l*8 + j] = Wr[k][col]
__global__ __launch_bounds__(512) void pack_wr(const float* __restrict__ Wr,
                                               _Float16* __restrict__ P)
{
    int idx = blockIdx.x * 512 + threadIdx.x;   // 64 blocks -> 32768
    int l   = idx & 63;
    int kt  = (idx >> 6) & 7;
    int T   = idx >> 9;                         // 0..63
    int p = T >> 5, q = (T >> 3) & 3, w = T & 7;
    int col = q * 256 + p * 128 + w * 16 + (l & 15);
    int k0  = kt * 32 + (l >> 4) * 8;
    half8 v;
#pragma unroll
    for (int j = 0; j < 8; ++j) v[j] = (_Float16)Wr[(k0 + j) * 1024 + col];
    *reinterpret_cast<half8*>(P + (size_t)idx * 8) = v;
}

__global__ __launch_bounds__(512, 2) void lstm_pair(
    const float* __restrict__ x_in,   // [1024][128][3]
    const float* __restrict__ Wk,     // [3][1024]
    const float* __restrict__ bias,   // [1024]
    const float* __restrict__ Wd,     // [256][3]
    const float* __restrict__ bd,     // [3]
    const _Float16* __restrict__ WrP, // packed B-frags
    u32*   __restrict__ hexT,         // [2 par][64 grp][2 mem][2048] tagged words
    float* __restrict__ out)          // [1024][32][3]
{
    __shared__ float                xs[16 * TIN * FIN];  // 24 KB staged inputs
    __shared__ alignas(16) _Float16 hfull[2][4096];      // full h, A-frag order
    __shared__ float                pred_buf[16][4];     // fed-back prediction

    const int tid  = threadIdx.x;
    const int w    = tid >> 6;            // wave 0..7
    const int l    = tid & 63;
    const int n    = l & 15;
    const int row0 = (l >> 4) * 4;        // MFMA C rows for this lane
    const int bid  = blockIdx.x;
    const int p    = (bid >> 3) & 1;      // member: units [p*128,(p+1)*128)
    const int pp   = 1 - p;
    const int g    = (bid & 7) + 8 * (bid >> 4);   // group 0..63; pair = same XCD

    // ---- prologue ----
    const float* xsrc = x_in + (size_t)g * 16 * TIN * FIN;
    for (int i = tid; i < 16 * TIN * FIN; i += 512) xs[i] = xsrc[i];

    half8 bfr[4][8];                      // weight slice (lives in AGPRs)
#pragma unroll
    for (int q = 0; q < 4; ++q)
#pragma unroll
        for (int kt = 0; kt < 8; ++kt)
            bfr[q][kt] = *reinterpret_cast<const half8*>(
                WrP + (((size_t)(p * 32 + q * 8 + w) * 8 + kt) * 512 + l * 8));

    float b_r[4], wk_r[4][3];
#pragma unroll
    for (int q = 0; q < 4; ++q) {
        int col = q * 256 + p * 128 + w * 16 + n;
        b_r[q] = bias[col];
#pragma unroll
        for (int f = 0; f < 3; ++f) wk_r[q][f] = Wk[f * 1024 + col];
    }
    float wd_r[4][3];                     // head: lane l covers units 4l..4l+3
#pragma unroll
    for (int j = 0; j < 4; ++j)
#pragma unroll
        for (int f = 0; f < 3; ++f) wd_r[j][f] = Wd[(4 * l + j) * 3 + f];
    const float bd0 = bd[0], bd1 = bd[1], bd2 = bd[2];

    float c_st[4] = {0.f, 0.f, 0.f, 0.f};
    const int hloc = (w >> 1) * 512 + ((2 * w + (n >> 3)) & 3) * 128
                   + row0 * 8 + (n & 7);
    const int hpos = p * 2048 + hloc;     // own h position in hfull

    __syncthreads();

    for (int t = 0; t <= LASTT; ++t) {
        const int par_rd = (t - 1) & 1;   // parity holding h_{t-1} (t>0)
        const bool dec = (t >= TIN);

        // ---- (1) own-half compute first (no peer dependency) ----
        f32x4 acc[4];
#pragma unroll
        for (int q = 0; q < 4; ++q)
#pragma unroll
            for (int r = 0; r < 4; ++r) acc[q][r] = b_r[q];
        if (!dec) {                          // warmup (incl. t=0): x@Wk now
#pragma unroll
            for (int r = 0; r < 4; ++r) {
                const float* xp = &xs[((row0 + r) * TIN + t) * 3];
                float x0 = xp[0], x1 = xp[1], x2 = xp[2];
#pragma unroll
                for (int q = 0; q < 4; ++q)
                    acc[q][r] += x0 * wk_r[q][0] + x1 * wk_r[q][1] + x2 * wk_r[q][2];
            }
        }
        if (t > 0) {
#pragma unroll
            for (int kk = 0; kk < 4; ++kk) {
                half8 a = *reinterpret_cast<const half8*>(
                    &hfull[par_rd][(4 * p + kk) * 512 + l * 8]);
#pragma unroll
                for (int q = 0; q < 4; ++q)
                    acc[q] = __builtin_amdgcn_mfma_f32_16x16x32_f16(a, bfr[q][4 * p + kk], acc[q], 0, 0, 0);
            }
        }

        // ---- (2) LATE one-shot tagged load; rare predicated retry ----
        if (t > 0) {
            __builtin_amdgcn_sched_barrier(0);   // forbid hoisting loads above MFMAs
            const u64* src = reinterpret_cast<const u64*>(
                hexT + (((size_t)par_rd * 64 + g) * 2 + pp) * 2048) + tid * 2;
            const u64 msk = 0x0000FFFF0000FFFFull;
            const u64 tg2 = (u64)(u32)(t - 1) * 0x0000000100000001ull;
            u64 w0 = __hip_atomic_load(src + 0, __ATOMIC_RELAXED, __HIP_MEMORY_SCOPE_AGENT);
            u64 w1 = __hip_atomic_load(src + 1, __ATOMIC_RELAXED, __HIP_MEMORY_SCOPE_AGENT);
            while (((w0 & msk) != tg2) || ((w1 & msk) != tg2)) {
                __builtin_amdgcn_s_sleep(4);     // ~256 cyc backoff, failed threads only
                w0 = __hip_atomic_load(src + 0, __ATOMIC_RELAXED, __HIP_MEMORY_SCOPE_AGENT);
                w1 = __hip_atomic_load(src + 1, __ATOMIC_RELAXED, __HIP_MEMORY_SCOPE_AGENT);
            }
            u64 hv = ((w0 >> 16) & 0xFFFFull)
                   | ((w0 >> 48) << 16)
                   | (((w1 >> 16) & 0xFFFFull) << 32)
                   | ((w1 >> 48) << 48);
            reinterpret_cast<u64*>(&hfull[par_rd][pp * 2048])[tid] = hv;
            __syncthreads();                     // B1: peer half broadcast
        }

        // ---- head phase (t>=128): pred_s from h_{t-1}, s = t-128 ----
        if (dec) {
            const int s = t - TIN;
#pragma unroll
            for (int rr = 0; rr < 2; ++rr) {
                int row = 2 * w + rr;            // wave w reduces batch rows 2w, 2w+1
                const _Float16* hb = &hfull[par_rd][(l >> 3) * 512
                                   + ((l >> 1) & 3) * 128 + row * 8 + 4 * (l & 1)];
                float p0 = 0.f, p1 = 0.f, p2 = 0.f;
#pragma unroll
                for (int j = 0; j < 4; ++j) {
                    float hj = (float)hb[j];
                    p0 += hj * wd_r[j][0];
                    p1 += hj * wd_r[j][1];
                    p2 += hj * wd_r[j][2];
                }
#pragma unroll
                for (int o = 32; o > 0; o >>= 1) {
                    p0 += __shfl_xor(p0, o);
                    p1 += __shfl_xor(p1, o);
                    p2 += __shfl_xor(p2, o);
                }
                if (l == 0) {
                    p0 += bd0; p1 += bd1; p2 += bd2;
                    pred_buf[row][0] = p0; pred_buf[row][1] = p1; pred_buf[row][2] = p2;
                    if (p == 0) {
                        float* op = out + ((size_t)(g * 16 + row) * OSTEPS + s) * 3;
                        op[0] = p0; op[1] = p1; op[2] = p2;
                    }
                }
            }
            __syncthreads();                     // B2: pred_buf ready
            if (t == LASTT) break;               // s=31 stored; done
            // decode: x@Wk with x = pred
#pragma unroll
            for (int r = 0; r < 4; ++r) {
                float x0 = pred_buf[row0 + r][0];
                float x1 = pred_buf[row0 + r][1];
                float x2 = pred_buf[row0 + r][2];
#pragma unroll
                for (int q = 0; q < 4; ++q)
                    acc[q][r] += x0 * wk_r[q][0] + x1 * wk_r[q][1] + x2 * wk_r[q][2];
            }
        }

        // ---- (3) peer-half MFMAs ----
        if (t > 0) {
#pragma unroll
            for (int kk = 0; kk < 4; ++kk) {
                half8 a = *reinterpret_cast<const half8*>(
                    &hfull[par_rd][(4 * pp + kk) * 512 + l * 8]);
#pragma unroll
                for (int q = 0; q < 4; ++q)
                    acc[q] = __builtin_amdgcn_mfma_f32_16x16x32_f16(a, bfr[q][4 * pp + kk], acc[q], 0, 0, 0);
            }
        }

        // ---- gates (in-lane), c update, own-half h -> LDS ----
        const int par_wr = t & 1;
#pragma unroll
        for (int r = 0; r < 4; ++r) {
            float iv = sigm(acc[0][r]);
            float fv = sigm(acc[1][r]);
            float gv = tanh_f(acc[2][r]);
            float ov = sigm(acc[3][r]);
            float cc = fv * c_st[r] + iv * gv;
            c_st[r] = cc;
            hfull[par_wr][hpos + r * 8] = (_Float16)(ov * tanh_f(cc));
        }
        __syncthreads();                         // B3: own half complete in LDS

        // ---- (4) publish: coalesced tagged stores (2 u64 per thread) ----
        {
            u64 d = reinterpret_cast<const u64*>(&hfull[par_wr][p * 2048])[tid];
            u32 t0 = ((u32)(d & 0xFFFF)         << 16) | (u32)t;
            u32 t1 = ((u32)((d >> 16) & 0xFFFF) << 16) | (u32)t;
            u32 t2 = ((u32)((d >> 32) & 0xFFFF) << 16) | (u32)t;
            u32 t3 = ((u32)(d >> 48)            << 16) | (u32)t;
            u64* dst = reinterpret_cast<u64*>(
                hexT + (((size_t)par_wr * 64 + g) * 2 + p) * 2048) + tid * 2;
            __hip_atomic_store(dst + 0, (u64)t0 | ((u64)t1 << 32),
                               __ATOMIC_RELAXED, __HIP_MEMORY_SCOPE_AGENT);
            __hip_atomic_store(dst + 1, (u64)t2 | ((u64)t3 << 32),
                               __ATOMIC_RELAXED, __HIP_MEMORY_SCOPE_AGENT);
        }
        // tags self-validate: no drain / counter / trailing barrier needed.
    }
}

extern "C" void kernel_launch(void* const* d_in, const int* in_sizes, int n_in,
                              void* d_out, int out_size, void* d_ws, size_t ws_size,
                              hipStream_t stream)
{
    const float* x  = (const float*)d_in[0];
    const float* Wk = (const float*)d_in[1];
    const float* Wr = (const float*)d_in[2];
    const float* b  = (const float*)d_in[3];
    const float* Wd = (const float*)d_in[4];
    const float* bd = (const float*)d_in[5];
    float* out = (float*)d_out;

    // d_ws: [0,512K) WrP | [512K, 512K+2M) tagged hex
    _Float16* WrP  = (_Float16*)d_ws;
    u32*      hexT = (u32*)((char*)d_ws + 524288);

    hipMemsetAsync(hexT, 0xFF, 2097152, stream);    // tag 0xFFFF: never matches
    pack_wr<<<64, 512, 0, stream>>>(Wr, WrP);
    lstm_pair<<<128, 512, 0, stream>>>(x, Wk, b, Wd, bd, WrP, hexT, out);
}

// Round 11
// 464.923 us; speedup vs baseline: 3.5678x; 3.1766x over previous
//
#include <hip/hip_runtime.h>

// FeedBack LSTM: B=1024, T_in=128, F=3, UNITS=256, out_steps=32.
// R11 = R6's EXACT loop shape (monolithic 32-MFMA block, VGPR=128 weight
// residency -- R8/R9/R10 post-mortem: splitting the MFMA cluster demoted
// bfr to memory, 10us/step) with only the exchange protocol swapped:
//   publish: coalesced tagged u64 stores (h16<<16|t per u32) -- no drain,
//            no counter (saves 2 serial L3 RTs vs R6).
//   acquire: tid0-ONLY sentinel poll (16B, one line -- R6-proven quiet),
//            barrier, then ONE bulk tagged load; per-thread predicated
//            retry with s_sleep(8) backoff as a rarely-taken backstop.
// Safety: parity slots + exact-tag match (R7/R10 argument); tag and its 16
// data bits share a u32 (no torn reads); producer's t+1 overwrite of a slot
// happens-after consumer's t-1 read via data dependence through h.

#define TIN    128
#define FIN    3
#define OSTEPS 32
#define LASTT  (TIN + OSTEPS - 1)   // t = 0..159; t==159 is head-only

typedef float    f32x4 __attribute__((ext_vector_type(4)));
typedef _Float16 half8 __attribute__((ext_vector_type(8)));
typedef unsigned long long u64;
typedef unsigned int u32;

__device__ __forceinline__ float fast_rcp(float x) { return __builtin_amdgcn_rcpf(x); }
__device__ __forceinline__ float sigm(float x)  { return fast_rcp(1.0f + __expf(-x)); }
__device__ __forceinline__ float tanh_f(float x){ return 1.0f - 2.0f * fast_rcp(__expf(2.0f * x) + 1.0f); }

// Pack Wr [256][1024] fp32 -> fp16 B-frags. Tile T = p*32 + q*8 + w covers
// cols q*256 + p*128 + w*16 + (l&15); k = kt*32 + (l>>4)*8 + j.
// P[(T*8+kt)*512 + l*8 + j] = Wr[k][col]
__global__ __launch_bounds__(512) void pack_wr(const float* __restrict__ Wr,
                                               _Float16* __restrict__ P)
{
    int idx = blockIdx.x * 512 + threadIdx.x;   // 64 blocks -> 32768
    int l   = idx & 63;
    int kt  = (idx >> 6) & 7;
    int T   = idx >> 9;                         // 0..63
    int p = T >> 5, q = (T >> 3) & 3, w = T & 7;
    int col = q * 256 + p * 128 + w * 16 + (l & 15);
    int k0  = kt * 32 + (l >> 4) * 8;
    half8 v;
#pragma unroll
    for (int j = 0; j < 8; ++j) v[j] = (_Float16)Wr[(k0 + j) * 1024 + col];
    *reinterpret_cast<half8*>(P + (size_t)idx * 8) = v;
}

__global__ __launch_bounds__(512, 2) void lstm_pair(
    const float* __restrict__ x_in,   // [1024][128][3]
    const float* __restrict__ Wk,     // [3][1024]
    const float* __restrict__ bias,   // [1024]
    const float* __restrict__ Wd,     // [256][3]
    const float* __restrict__ bd,     // [3]
    const _Float16* __restrict__ WrP, // packed B-frags
    u32*   __restrict__ hexT,         // [2 par][64 grp][2 mem][2048] tagged words
    float* __restrict__ out)          // [1024][32][3]
{
    __shared__ float                xs[16 * TIN * FIN];  // 24 KB staged inputs
    __shared__ alignas(16) _Float16 hfull[2][4096];      // full h, A-frag order
    __shared__ float                pred_buf[16][4];     // fed-back prediction

    const int tid  = threadIdx.x;
    const int w    = tid >> 6;            // wave 0..7
    const int l    = tid & 63;
    const int n    = l & 15;
    const int row0 = (l >> 4) * 4;        // MFMA C rows for this lane
    const int bid  = blockIdx.x;
    const int p    = (bid >> 3) & 1;      // member: units [p*128,(p+1)*128)
    const int pp   = 1 - p;
    const int g    = (bid & 7) + 8 * (bid >> 4);   // group 0..63; pair = same XCD

    // ---- prologue ----
    const float* xsrc = x_in + (size_t)g * 16 * TIN * FIN;
    for (int i = tid; i < 16 * TIN * FIN; i += 512) xs[i] = xsrc[i];

    half8 bfr[4][8];                      // weight slice (AGPR/VGPR resident)
#pragma unroll
    for (int q = 0; q < 4; ++q)
#pragma unroll
        for (int kt = 0; kt < 8; ++kt)
            bfr[q][kt] = *reinterpret_cast<const half8*>(
                WrP + (((size_t)(p * 32 + q * 8 + w) * 8 + kt) * 512 + l * 8));

    float b_r[4], wk_r[4][3];
#pragma unroll
    for (int q = 0; q < 4; ++q) {
        int col = q * 256 + p * 128 + w * 16 + n;
        b_r[q] = bias[col];
#pragma unroll
        for (int f = 0; f < 3; ++f) wk_r[q][f] = Wk[f * 1024 + col];
    }
    float wd_r[4][3];                     // head: lane l covers units 4l..4l+3
#pragma unroll
    for (int j = 0; j < 4; ++j)
#pragma unroll
        for (int f = 0; f < 3; ++f) wd_r[j][f] = Wd[(4 * l + j) * 3 + f];
    const float bd0 = bd[0], bd1 = bd[1], bd2 = bd[2];

    float c_st[4] = {0.f, 0.f, 0.f, 0.f};
    const int hloc = (w >> 1) * 512 + ((2 * w + (n >> 3)) & 3) * 128
                   + row0 * 8 + (n & 7);
    const int hpos = p * 2048 + hloc;     // own h position in hfull

    __syncthreads();

    for (int t = 0; t <= LASTT; ++t) {
        const int par_rd = (t - 1) & 1;   // parity holding h_{t-1} (t>0)

        // ---- acquire h_{t-1}: tid0 sentinel poll -> barrier -> bulk load ----
        if (t > 0) {
            const u64* src = reinterpret_cast<const u64*>(
                hexT + (((size_t)par_rd * 64 + g) * 2 + pp) * 2048);
            const u64 msk = 0x0000FFFF0000FFFFull;
            const u64 tg2 = (u64)(u32)(t - 1) * 0x0000000100000001ull;
            if (tid == 0) {               // quiet: one line, one poller
                u64 s0, s1;
                do {
                    s0 = __hip_atomic_load(src + 0, __ATOMIC_RELAXED, __HIP_MEMORY_SCOPE_AGENT);
                    s1 = __hip_atomic_load(src + 1, __ATOMIC_RELAXED, __HIP_MEMORY_SCOPE_AGENT);
                } while (((s0 & msk) != tg2) || ((s1 & msk) != tg2));
            }
            __syncthreads();              // B0: peer burst confirmed in flight
            u64 w0 = __hip_atomic_load(src + tid * 2 + 0, __ATOMIC_RELAXED, __HIP_MEMORY_SCOPE_AGENT);
            u64 w1 = __hip_atomic_load(src + tid * 2 + 1, __ATOMIC_RELAXED, __HIP_MEMORY_SCOPE_AGENT);
            while (((w0 & msk) != tg2) || ((w1 & msk) != tg2)) {   // rare backstop
                __builtin_amdgcn_s_sleep(8);
                w0 = __hip_atomic_load(src + tid * 2 + 0, __ATOMIC_RELAXED, __HIP_MEMORY_SCOPE_AGENT);
                w1 = __hip_atomic_load(src + tid * 2 + 1, __ATOMIC_RELAXED, __HIP_MEMORY_SCOPE_AGENT);
            }
            u64 hv = ((w0 >> 16) & 0xFFFFull)
                   | ((w0 >> 48) << 16)
                   | (((w1 >> 16) & 0xFFFFull) << 32)
                   | ((w1 >> 48) << 48);
            reinterpret_cast<u64*>(&hfull[par_rd][pp * 2048])[tid] = hv;
            __syncthreads();              // B1: peer half broadcast
        }

        // ---- head phase (t>=128): pred_s from h_{t-1}, s = t-128 ----
        if (t >= TIN) {
            const int s = t - TIN;
#pragma unroll
            for (int rr = 0; rr < 2; ++rr) {
                int row = 2 * w + rr;     // wave w reduces batch rows 2w, 2w+1
                const _Float16* hb = &hfull[par_rd][(l >> 3) * 512
                                   + ((l >> 1) & 3) * 128 + row * 8 + 4 * (l & 1)];
                float p0 = 0.f, p1 = 0.f, p2 = 0.f;
#pragma unroll
                for (int j = 0; j < 4; ++j) {
                    float hj = (float)hb[j];
                    p0 += hj * wd_r[j][0];
                    p1 += hj * wd_r[j][1];
                    p2 += hj * wd_r[j][2];
                }
#pragma unroll
                for (int o = 32; o > 0; o >>= 1) {
                    p0 += __shfl_xor(p0, o);
                    p1 += __shfl_xor(p1, o);
                    p2 += __shfl_xor(p2, o);
                }
                if (l == 0) {
                    p0 += bd0; p1 += bd1; p2 += bd2;
                    pred_buf[row][0] = p0; pred_buf[row][1] = p1; pred_buf[row][2] = p2;
                    if (p == 0) {
                        float* op = out + ((size_t)(g * 16 + row) * OSTEPS + s) * 3;
                        op[0] = p0; op[1] = p1; op[2] = p2;
                    }
                }
            }
            __syncthreads();              // B2: pred_buf ready
            if (t == LASTT) break;        // s=31 stored; done
        }

        // ---- A-fragments (static indices; zeros at t=0) ----
        half8 a[8];
        if (t > 0) {
#pragma unroll
            for (int kt = 0; kt < 8; ++kt)
                a[kt] = *reinterpret_cast<const half8*>(&hfull[par_rd][kt * 512 + l * 8]);
        } else {
            half8 az = {};
#pragma unroll
            for (int kt = 0; kt < 8; ++kt) a[kt] = az;
        }

        // ---- x for this cell step ----
        float xv[4][3];
#pragma unroll
        for (int r = 0; r < 4; ++r) {
            int row = row0 + r;
            if (t >= TIN) {
                xv[r][0] = pred_buf[row][0];
                xv[r][1] = pred_buf[row][1];
                xv[r][2] = pred_buf[row][2];
            } else {
                const float* xp = &xs[(row * TIN + t) * 3];
                xv[r][0] = xp[0]; xv[r][1] = xp[1]; xv[r][2] = xp[2];
            }
        }

        // ---- z = b + x@Wk + h@Wr (32 MFMA, MONOLITHIC -- keep bfr resident) ----
        f32x4 acc[4];
#pragma unroll
        for (int q = 0; q < 4; ++q)
#pragma unroll
            for (int r = 0; r < 4; ++r)
                acc[q][r] = b_r[q] + xv[r][0] * wk_r[q][0]
                          + xv[r][1] * wk_r[q][1] + xv[r][2] * wk_r[q][2];
#pragma unroll
        for (int kt = 0; kt < 8; ++kt)
#pragma unroll
            for (int q = 0; q < 4; ++q)
                acc[q] = __builtin_amdgcn_mfma_f32_16x16x32_f16(a[kt], bfr[q][kt], acc[q], 0, 0, 0);

        // ---- gates (in-lane), c update, own-half h -> LDS ----
        const int par_wr = t & 1;
#pragma unroll
        for (int r = 0; r < 4; ++r) {
            float iv = sigm(acc[0][r]);
            float fv = sigm(acc[1][r]);
            float gv = tanh_f(acc[2][r]);
            float ov = sigm(acc[3][r]);
            float cc = fv * c_st[r] + iv * gv;
            c_st[r] = cc;
            hfull[par_wr][hpos + r * 8] = (_Float16)(ov * tanh_f(cc));
        }
        __syncthreads();                  // B3: own half complete in LDS

        // ---- publish: coalesced tagged stores; no drain, no counter ----
        {
            u64 d = reinterpret_cast<const u64*>(&hfull[par_wr][p * 2048])[tid];
            u32 t0 = ((u32)(d & 0xFFFF)         << 16) | (u32)t;
            u32 t1 = ((u32)((d >> 16) & 0xFFFF) << 16) | (u32)t;
            u32 t2 = ((u32)((d >> 32) & 0xFFFF) << 16) | (u32)t;
            u32 t3 = ((u32)(d >> 48)            << 16) | (u32)t;
            u64* dst = reinterpret_cast<u64*>(
                hexT + (((size_t)par_wr * 64 + g) * 2 + p) * 2048) + tid * 2;
            __hip_atomic_store(dst + 0, (u64)t0 | ((u64)t1 << 32),
                               __ATOMIC_RELAXED, __HIP_MEMORY_SCOPE_AGENT);
            __hip_atomic_store(dst + 1, (u64)t2 | ((u64)t3 << 32),
                               __ATOMIC_RELAXED, __HIP_MEMORY_SCOPE_AGENT);
        }
    }
}

extern "C" void kernel_launch(void* const* d_in, const int* in_sizes, int n_in,
                              void* d_out, int out_size, void* d_ws, size_t ws_size,
                              hipStream_t stream)
{
    const float* x  = (const float*)d_in[0];
    const float* Wk = (const float*)d_in[1];
    const float* Wr = (const float*)d_in[2];
    const float* b  = (const float*)d_in[3];
    const float* Wd = (const float*)d_in[4];
    const float* bd = (const float*)d_in[5];
    float* out = (float*)d_out;

    // d_ws: [0,512K) WrP | [512K, 512K+2M) tagged hex
    _Float16* WrP  = (_Float16*)d_ws;
    u32*      hexT = (u32*)((char*)d_ws + 524288);

    hipMemsetAsync(hexT, 0xFF, 2097152, stream);    // tag 0xFFFF: never matches
    pack_wr<<<64, 512, 0, stream>>>(Wr, WrP);
    lstm_pair<<<128, 512, 0, stream>>>(x, Wk, b, Wd, bd, WrP, hexT, out);
}